// Round 22
// baseline (243.157 us; speedup 1.0000x reference)
//
#include <hip/hip_runtime.h>
#include <math.h>

typedef __attribute__((ext_vector_type(8))) short v8s;
typedef __attribute__((ext_vector_type(4))) float v4f;
typedef __attribute__((ext_vector_type(2))) float v2f;
typedef __attribute__((ext_vector_type(16))) float v16f;
typedef __attribute__((ext_vector_type(4))) unsigned int v4u;
typedef __attribute__((ext_vector_type(2))) unsigned int v2u;

#define MFMA16(a,b,c) __builtin_amdgcn_mfma_f32_16x16x32_bf16(a,b,c,0,0,0)
#define MFMA32(a,b,c) __builtin_amdgcn_mfma_f32_32x32x16_bf16(a,b,c,0,0,0)
#define QSCALE 0.18033688011112042f  /* 0.125 * log2(e) */
#define MFIX   12.0f                 /* fixed softmax shift (exp2 domain) */

typedef const __attribute__((address_space(1))) void* gp1_t;
typedef __attribute__((address_space(3))) void* lp3_t;
__device__ __forceinline__ void gll16(const void* g, void* l){
  __builtin_amdgcn_global_load_lds((gp1_t)g, (lp3_t)l, 16, 0, 0);
}
#define VMCNT(n) asm volatile("s_waitcnt vmcnt(" #n ")" ::: "memory")

__device__ __forceinline__ unsigned short f2b(float f){
  unsigned u = __builtin_bit_cast(unsigned, f);
  u += 0x7FFFu + ((u>>16)&1u);
  return (unsigned short)(u>>16);
}
__device__ __forceinline__ float b2f(unsigned short u){
  return __builtin_bit_cast(float, ((unsigned)u)<<16);
}
__device__ __forceinline__ unsigned cvtpk(float lo, float hi){
  unsigned r;
  asm("v_cvt_pk_bf16_f32 %0, %1, %2" : "=v"(r) : "v"(lo), "v"(hi));
  return r;
}
__device__ __forceinline__ float gelu_exact(float x){
  return 0.5f*x*(1.0f + erff(x*0.70710678118654752f));
}

// ---------------- LayerNorm (ddof=1, sd+eps) -> bf16 out (used for ln2) ----
__global__ __launch_bounds__(256) void ln_kernel(const float* __restrict__ x,
    const float* __restrict__ alpha, const float* __restrict__ bias,
    unsigned short* __restrict__ out)
{
  const int D = 1024;
  int row = blockIdx.x;
  int tid = threadIdx.x;
  const float* xr = x + (size_t)row*D;
  v4f v = ((const v4f*)xr)[tid];
  float s  = v[0]+v[1]+v[2]+v[3];
  float s2 = v[0]*v[0]+v[1]*v[1]+v[2]*v[2]+v[3]*v[3];
  #pragma unroll
  for (int off=1; off<64; off<<=1){ s += __shfl_xor(s, off); s2 += __shfl_xor(s2, off); }
  __shared__ float red[8];
  int w = tid>>6;
  if ((tid&63)==0){ red[w]=s; red[4+w]=s2; }
  __syncthreads();
  s  = red[0]+red[1]+red[2]+red[3];
  s2 = red[4]+red[5]+red[6]+red[7];
  float mu  = s*(1.0f/D);
  float var = (s2 - (float)D*mu*mu)*(1.0f/(D-1));
  float inv = 1.0f/(sqrtf(fmaxf(var,0.0f)) + 1e-6f);
  v4f a  = ((const v4f*)alpha)[tid];
  v4f bi = ((const v4f*)bias)[tid];
  unsigned short o[4];
  #pragma unroll
  for (int i=0;i<4;i++) o[i] = f2b(a[i]*(v[i]-mu)*inv + bi[i]);
  v2u pk; pk[0] = (unsigned)o[0] | ((unsigned)o[1]<<16);
          pk[1] = (unsigned)o[2] | ((unsigned)o[3]<<16);
  ((v2u*)(out + (size_t)row*D))[tid] = pk;
}

// ---- fused prologue: weight transposes + mask flags + ln1, block-ranged ----
__global__ __launch_bounds__(256) void preprocess(
    const float* __restrict__ Wq, const float* __restrict__ Wk,
    const float* __restrict__ Wv, const float* __restrict__ Wo,
    const float* __restrict__ W1, const float* __restrict__ W2,
    const int* __restrict__ mask, const float* __restrict__ x,
    const float* __restrict__ alpha1, const float* __restrict__ bias1,
    unsigned short* __restrict__ wqkvT, unsigned short* __restrict__ woT,
    unsigned short* __restrict__ w1T, unsigned short* __restrict__ w2T,
    unsigned char* __restrict__ flags, unsigned short* __restrict__ x2b)
{
  __shared__ float t[32][33];
  __shared__ float red[8];
  __shared__ int f[4];
  int bid = blockIdx.x;
  int tid = threadIdx.x;
  if (bid < 8192){
    const float* in; unsigned short* out; int K, N, idx;
    if (bid < 3072){
      int m = bid >> 10; idx = bid & 1023;
      in = (m==0)?Wq:(m==1)?Wk:Wv; out = wqkvT + (size_t)m*1024*1024; K=1024; N=1024;
    } else if (bid < 4096){ idx = bid-3072; in=Wo; out=woT; K=1024; N=1024; }
    else if (bid < 6144){   idx = bid-4096; in=W1; out=w1T; K=1024; N=2048; }
    else {                  idx = bid-6144; in=W2; out=w2T; K=2048; N=1024; }
    int ntiles = N >> 5;
    int n0 = (idx % ntiles)*32, k0 = (idx / ntiles)*32;
    int tx = tid & 31, ty = tid >> 5;
    #pragma unroll
    for (int j=0;j<4;j++) t[ty+8*j][tx] = in[(size_t)(k0+ty+8*j)*N + n0+tx];
    __syncthreads();
    #pragma unroll
    for (int j=0;j<4;j++) out[(size_t)(n0+ty+8*j)*K + k0+tx] = f2b(t[tx][ty+8*j]);
  } else if (bid < 10240){
    const int S = 2048;
    int idx = bid - 8192;
    int kt = idx & 31, qt = (idx>>5)&31, b = idx>>10;
    const int* mp = mask + (size_t)b*S*S + (size_t)(qt*64)*S + kt*64;
    int ok = 1;
    #pragma unroll
    for (int i=0;i<16;i++){
      int e = tid + i*256;
      int row = e>>6, col = e&63;
      ok &= (mp[(size_t)row*S + col] != 0);
    }
    ok = __all(ok) ? 1 : 0;
    if ((tid&63)==0) f[tid>>6] = ok;
    __syncthreads();
    if (tid==0) flags[idx] = (unsigned char)(f[0]&f[1]&f[2]&f[3]);
  } else {
    const int D = 1024;
    int row = bid - 10240;
    const float* xr = x + (size_t)row*D;
    v4f v = ((const v4f*)xr)[tid];
    float s  = v[0]+v[1]+v[2]+v[3];
    float s2 = v[0]*v[0]+v[1]*v[1]+v[2]*v[2]+v[3]*v[3];
    #pragma unroll
    for (int off=1; off<64; off<<=1){ s += __shfl_xor(s, off); s2 += __shfl_xor(s2, off); }
    int w = tid>>6;
    if ((tid&63)==0){ red[w]=s; red[4+w]=s2; }
    __syncthreads();
    s  = red[0]+red[1]+red[2]+red[3];
    s2 = red[4]+red[5]+red[6]+red[7];
    float mu  = s*(1.0f/D);
    float var = (s2 - (float)D*mu*mu)*(1.0f/(D-1));
    float inv = 1.0f/(sqrtf(fmaxf(var,0.0f)) + 1e-6f);
    v4f a  = ((const v4f*)alpha1)[tid];
    v4f bi = ((const v4f*)bias1)[tid];
    unsigned short o[4];
    #pragma unroll
    for (int i=0;i<4;i++) o[i] = f2b(a[i]*(v[i]-mu)*inv + bi[i]);
    v2u pk; pk[0] = (unsigned)o[0] | ((unsigned)o[1]<<16);
            pk[1] = (unsigned)o[2] | ((unsigned)o[3]<<16);
    ((v2u*)(x2b + (size_t)row*D))[tid] = pk;
  }
}

// ---------------- fused QKV GEMM (128², 3buf); V written directly as vT -----
__global__ __launch_bounds__(256) void gemm_qkv(
    const unsigned short* __restrict__ A, const unsigned short* __restrict__ Bt,
    const float* __restrict__ bq, const float* __restrict__ bk, const float* __restrict__ bv,
    unsigned short* __restrict__ qB, unsigned short* __restrict__ kB,
    unsigned short* __restrict__ vT)
{
  const int K = 1024, N = 1024;
  __shared__ unsigned short As[3][128][32];
  __shared__ unsigned short Bs[3][128][32];
  int m0 = blockIdx.x*128;
  int ny = blockIdx.y;              // 0..23
  int seg = ny>>3;
  int n0g = ny*128;
  int tid = threadIdx.x;
  int w = tid>>6, l = tid&63;
  int wm = (w>>1)*64, wn = (w&1)*64;
  int r16 = l&15, kq = l>>4;
  v4f acc[4][4] = {};
  int t4 = tid>>2, c8 = (tid&3)*8;
  const unsigned short* Ag = A  + (size_t)(m0 + t4)*K + c8;
  const unsigned short* Bg = Bt + (size_t)(n0g + t4)*K + c8;
  auto stageG = [&](int kb, int idx){
    char* a = (char*)&As[idx][0][0] + w*1024;
    char* b = (char*)&Bs[idx][0][0] + w*1024;
    gll16(Ag + kb,                a);
    gll16(Ag + (size_t)64*K + kb, a + 4096);
    gll16(Bg + kb,                b);
    gll16(Bg + (size_t)64*K + kb, b + 4096);
  };
  const int nk = K/32;
  stageG(0, 0); stageG(32, 1);
  for (int i=0; i<nk; i++){
    int cur = i%3;
    if (i+1 < nk) VMCNT(4); else VMCNT(0);
    __builtin_amdgcn_s_barrier();
    if (i+2 < nk) stageG((i+2)*32, (i+2)%3);
    v8s a[4], b[4];
    #pragma unroll
    for (int mi=0;mi<4;mi++) a[mi] = *(const v8s*)&As[cur][wm+mi*16+r16][kq*8];
    #pragma unroll
    for (int ni=0;ni<4;ni++) b[ni] = *(const v8s*)&Bs[cur][wn+ni*16+r16][kq*8];
    #pragma unroll
    for (int mi=0;mi<4;mi++)
      #pragma unroll
      for (int ni=0;ni<4;ni++)
        acc[mi][ni] = MFMA16(a[mi], b[ni], acc[mi][ni]);
  }
  int ncol0 = (ny&7)*128;
  if (seg < 2){
    unsigned short* ob = (seg==0) ? qB : kB;
    const float*    bp = (seg==0) ? bq : bk;
    float sc = (seg==0) ? QSCALE : 1.0f;
    #pragma unroll
    for (int mi=0;mi<4;mi++){
      #pragma unroll
      for (int ni=0;ni<4;ni++){
        int col = ncol0 + wn + ni*16 + r16;
        float bvv = bp[col];
        #pragma unroll
        for (int r=0;r<4;r++){
          int row = m0 + wm + mi*16 + kq*4 + r;
          ob[(size_t)row*N + col] = f2b((acc[mi][ni][r] + bvv)*sc);
        }
      }
    }
  } else {
    #pragma unroll
    for (int mi=0;mi<4;mi++){
      #pragma unroll
      for (int ni=0;ni<4;ni++){
        int col = ncol0 + wn + ni*16 + r16;
        int hh = col >> 6, dk = col & 63;
        float bvv = bv[col];
        int row = m0 + wm + mi*16 + kq*4;    // r = 0..3 consecutive
        int bb = row >> 11, s = row & 2047;
        v2u pk;
        pk[0] = cvtpk(acc[mi][ni][0]+bvv, acc[mi][ni][1]+bvv);
        pk[1] = cvtpk(acc[mi][ni][2]+bvv, acc[mi][ni][3]+bvv);
        *(v2u*)(vT + ((size_t)(bb*16+hh)*64 + dk)*2048 + s) = pk;
      }
    }
  }
}

// ---- 64x128 GEMM, BK=64, XOR-swizzled LDS (Wo, FF1, FF2) -------------------
// Per-wave staging: wave w stages A rows w*16..+15, B rows w*32..+31.
// MODE 1: outf = acc+bias+res ; MODE 2: outb = bf16(gelu(acc+bias))
// MODE 3: outf = gelu(acc+bias)+res
template<int MODE>
__global__ __launch_bounds__(256) void gemm64_bk64(
    const unsigned short* __restrict__ A, const unsigned short* __restrict__ Bt,
    const float* __restrict__ bias, const float* __restrict__ res,
    unsigned short* __restrict__ outb, float* __restrict__ outf,
    int M, int N, int K)
{
  __shared__ unsigned short As[3][64][64];    // 24 KB
  __shared__ unsigned short Bs[3][128][64];   // 48 KB
  int m0 = blockIdx.x*64, n0 = blockIdx.y*128;
  int tid = threadIdx.x;
  int w = tid>>6, l = tid&63;
  int wm = (w>>1)*32, wn = (w&1)*64;
  int r16 = l&15, kq = l>>4;
  v4f acc[2][4] = {};
  int srow8 = l>>3;                 // 0..7 within 8-row stripe
  int gsw   = (l&7) ^ srow8;        // pre-swizzled source granule (rule #21)
  auto stageG = [&](int kb, int idx){
    #pragma unroll
    for (int sub=0; sub<2; sub++){
      int row = w*16 + sub*8 + srow8;
      gll16(A + (size_t)(m0+row)*K + kb + gsw*8, &As[idx][w*16+sub*8][0]);
    }
    #pragma unroll
    for (int sub=0; sub<4; sub++){
      int row = w*32 + sub*8 + srow8;
      gll16(Bt + (size_t)(n0+row)*K + kb + gsw*8, &Bs[idx][w*32+sub*8][0]);
    }
  };
  const int nk = K/64;
  stageG(0, 0); stageG(64, 1);
  int rx = r16 & 7;
  for (int i=0; i<nk; i++){
    int cur = i%3;
    if (i+1 < nk) VMCNT(6); else VMCNT(0);
    __builtin_amdgcn_s_barrier();
    if (i+2 < nk) stageG((i+2)*64, (i+2)%3);
    #pragma unroll
    for (int ks=0; ks<2; ks++){
      int gl = ((ks*4 + kq) ^ rx)*8;
      v8s a[2], b[4];
      #pragma unroll
      for (int mi=0;mi<2;mi++) a[mi] = *(const v8s*)&As[cur][wm+mi*16+r16][gl];
      #pragma unroll
      for (int ni=0;ni<4;ni++) b[ni] = *(const v8s*)&Bs[cur][wn+ni*16+r16][gl];
      #pragma unroll
      for (int mi=0;mi<2;mi++)
        #pragma unroll
        for (int ni=0;ni<4;ni++)
          acc[mi][ni] = MFMA16(a[mi], b[ni], acc[mi][ni]);
    }
  }
  #pragma unroll
  for (int mi=0;mi<2;mi++){
    #pragma unroll
    for (int ni=0;ni<4;ni++){
      int col = n0 + wn + ni*16 + r16;
      float bv = bias[col];
      #pragma unroll
      for (int r=0;r<4;r++){
        int row = m0 + wm + mi*16 + kq*4 + r;
        float t = acc[mi][ni][r] + bv;
        if (MODE==2 || MODE==3) t = gelu_exact(t);
        if (MODE==2) outb[(size_t)row*N + col] = f2b(t);
        else         outf[(size_t)row*N + col] = t + res[(size_t)row*N + col];
      }
    }
  }
}

// -------- flash attention, 2-way SPLIT-KV, fixed-shift softmax --------------
__global__ __launch_bounds__(256, 4) void attn_kernel(
    const unsigned short* __restrict__ Q, const unsigned short* __restrict__ Kb,
    const unsigned short* __restrict__ vT, const int* __restrict__ mask,
    const unsigned char* __restrict__ flags,
    unsigned short* __restrict__ Opart, float* __restrict__ ml)
{
  const int S = 2048, D = 1024;
  __shared__ unsigned short Kb2[2][64][64];   // 16 KB, granule-swizzled
  __shared__ unsigned short Vb2[2][64][64];   // 16 KB, granule-swizzled
  int bid = (blockIdx.x & 7)*128 + (blockIdx.x >> 3);   // 1024 blocks, bijective
  int half = bid & 1;
  int qt = (bid >> 1) & 15;     // 128-row q tile
  int bh = bid >> 5;
  int b = bh >> 4, h = bh & 15;
  int tid = threadIdx.x, w = tid>>6, l = tid&63;
  int l31 = l & 31, hi = l >> 5;
  int pidx = (l ^ 32) << 2;
  const unsigned short* Qp  = Q  + (size_t)b*S*D + h*64;
  const unsigned short* Kp  = Kb + (size_t)b*S*D + h*64;
  const unsigned short* vTp = vT + (size_t)bh*64*S;
  int qrow = qt*128 + w*32 + l31;
  v8s qfr[4];
  #pragma unroll
  for (int ks=0;ks<4;ks++)
    qfr[ks] = *(const v8s*)(Qp + (size_t)qrow*D + ks*16 + hi*8);
  float l_run = 0.0f;
  v16f o0 = {}, o1 = {};
  const int* mp = mask + (size_t)b*S*S;
  const unsigned char* fl = flags + ((size_t)b*32 + qt*2)*32;
  int kt0 = half*16;
  unsigned long long okmask = __ballot( l < 16 ? ((fl[kt0+l] & fl[32+kt0+l]) != 0) : 1 );

  int srow = l>>3;
  int gsw  = (l&7) ^ srow;
  auto stage = [&](int ktg, int idx){
    int kt64 = ktg*64;
    #pragma unroll
    for (int sub=0; sub<2; sub++){
      int row = w*16 + sub*8 + srow;
      gll16(Kp  + (size_t)(kt64+row)*D + gsw*8, &Kb2[idx][w*16+sub*8][0]);
      gll16(vTp + (size_t)row*S + kt64 + gsw*8, &Vb2[idx][w*16+sub*8][0]);
    }
  };
  auto bfrag = [&](unsigned a0, unsigned a1, unsigned a4, unsigned a5) -> v8s {
    unsigned p0 = (unsigned)__builtin_amdgcn_ds_bpermute(pidx, (int)a0);
    unsigned p1 = (unsigned)__builtin_amdgcn_ds_bpermute(pidx, (int)a1);
    unsigned p4 = (unsigned)__builtin_amdgcn_ds_bpermute(pidx, (int)a4);
    unsigned p5 = (unsigned)__builtin_amdgcn_ds_bpermute(pidx, (int)a5);
    v4u pw;
    pw[0] = hi ? p4 : a0;
    pw[1] = hi ? p5 : a1;
    pw[2] = hi ? a4 : p0;
    pw[3] = hi ? a5 : p1;
    return __builtin_bit_cast(v8s, pw);
  };

  stage(kt0, 0);
  int cur = 0;
  for (int it=0; it<16; it++){
    __syncthreads();
    if (it+1 < 16) stage(kt0+it+1, cur^1);
    int ktg = kt0 + it;
    int l7 = l & 7;
    v16f s0 = {}, s1 = {};
    __builtin_amdgcn_s_setprio(1);
    #pragma unroll
    for (int ks=0; ks<4; ks++){
      v8s kf0 = *(const v8s*)&Kb2[cur][l31     ][(((ks*2) + hi) ^ l7)*8];
      v8s kf1 = *(const v8s*)&Kb2[cur][32 + l31][(((ks*2) + hi) ^ l7)*8];
      s0 = MFMA32(kf0, qfr[ks], s0);
      s1 = MFMA32(kf1, qfr[ks], s1);
    }
    __builtin_amdgcn_s_setprio(0);
    if (((~okmask) >> it) & 1ull){
      #pragma unroll
      for (int r=0;r<16;r++){
        int kvl = (r&3) + 8*(r>>2) + 4*hi;
        if (mp[(size_t)qrow*S + ktg*64 + kvl]      == 0) s0[r] = -3.0e38f;
        if (mp[(size_t)qrow*S + ktg*64 + 32 + kvl] == 0) s1[r] = -3.0e38f;
      }
    }
    #pragma unroll
    for (int r=0;r<16;r++){
      s0[r] = exp2f(s0[r] - MFIX);
      s1[r] = exp2f(s1[r] - MFIX);
    }
    float a0 = ((s0[0]+s0[1])+(s0[2]+s0[3])) + ((s0[4]+s0[5])+(s0[6]+s0[7]));
    float a1 = ((s0[8]+s0[9])+(s0[10]+s0[11])) + ((s0[12]+s0[13])+(s0[14]+s0[15]));
    float a2 = ((s1[0]+s1[1])+(s1[2]+s1[3])) + ((s1[4]+s1[5])+(s1[6]+s1[7]));
    float a3 = ((s1[8]+s1[9])+(s1[10]+s1[11])) + ((s1[12]+s1[13])+(s1[14]+s1[15]));
    float rs = (a0+a1) + (a2+a3);
    rs += __shfl_xor(rs, 32);
    l_run += rs;
    v8s pb0 = bfrag(cvtpk(s0[0],s0[1]),  cvtpk(s0[2],s0[3]),
                    cvtpk(s0[4],s0[5]),  cvtpk(s0[6],s0[7]));
    v8s pb1 = bfrag(cvtpk(s0[8],s0[9]),  cvtpk(s0[10],s0[11]),
                    cvtpk(s0[12],s0[13]),cvtpk(s0[14],s0[15]));
    v8s pb2 = bfrag(cvtpk(s1[0],s1[1]),  cvtpk(s1[2],s1[3]),
                    cvtpk(s1[4],s1[5]),  cvtpk(s1[6],s1[7]));
    v8s pb3 = bfrag(cvtpk(s1[8],s1[9]),  cvtpk(s1[10],s1[11]),
                    cvtpk(s1[12],s1[13]),cvtpk(s1[14],s1[15]));
    __builtin_amdgcn_s_setprio(1);
    #pragma unroll
    for (int kvs=0; kvs<4; kvs++){
      v8s pb = (kvs==0) ? pb0 : (kvs==1) ? pb1 : (kvs==2) ? pb2 : pb3;
      v8s vv0 = *(const v8s*)&Vb2[cur][l31     ][(((kvs*2) + hi) ^ l7)*8];
      v8s vv1 = *(const v8s*)&Vb2[cur][32 + l31][(((kvs*2) + hi) ^ l7)*8];
      o0 = MFMA32(vv0, pb, o0);
      o1 = MFMA32(vv1, pb, o1);
    }
    __builtin_amdgcn_s_setprio(0);
    cur ^= 1;
  }
  int rowg = b*S + qrow;
  unsigned short* Op = Opart + (size_t)half*4096*1024 + (size_t)rowg*1024 + h*64;
  #pragma unroll
  for (int p=0; p<8; p++){
    int dk = (p&1)*2 + 8*(p>>1) + 4*hi;
    *(unsigned*)(Op + dk)      = cvtpk(o0[2*p], o0[2*p+1]);
    *(unsigned*)(Op + 32 + dk) = cvtpk(o1[2*p], o1[2*p+1]);
  }
  if (!hi){
    float* mlp = ml + ((size_t)half*4096 + rowg)*32 + h*2;
    mlp[0] = l_run;
  }
}

// ---------------- combine the two kv-half partials -> bf16 attnB ------------
__global__ __launch_bounds__(256) void attn_combine(const unsigned short* __restrict__ Opart,
    const float* __restrict__ ml, unsigned short* __restrict__ outB)
{
  int row = blockIdx.x;            // 0..4095
  int t = threadIdx.x;
  int col = t*4;
  int head = col >> 6;
  float l1 = ml[(size_t)row*32 + head*2];
  float l2 = ml[((size_t)4096 + row)*32 + head*2];
  float inv = 1.0f / (l1 + l2);
  v2u au = *(const v2u*)(Opart + (size_t)row*1024 + col);
  v2u bu = *(const v2u*)(Opart + (size_t)4096*1024 + (size_t)row*1024 + col);
  float a0 = b2f((unsigned short)(au[0]&0xffff)), a1 = b2f((unsigned short)(au[0]>>16));
  float a2 = b2f((unsigned short)(au[1]&0xffff)), a3 = b2f((unsigned short)(au[1]>>16));
  float c0 = b2f((unsigned short)(bu[0]&0xffff)), c1 = b2f((unsigned short)(bu[0]>>16));
  float c2 = b2f((unsigned short)(bu[1]&0xffff)), c3 = b2f((unsigned short)(bu[1]>>16));
  v2u pk;
  pk[0] = cvtpk((a0 + c0)*inv, (a1 + c1)*inv);
  pk[1] = cvtpk((a2 + c2)*inv, (a3 + c3)*inv);
  *(v2u*)(outB + (size_t)row*1024 + col) = pk;
}

// ---------------- launcher ----------------
extern "C" void kernel_launch(void* const* d_in, const int* in_sizes, int n_in,
                              void* d_out, int out_size, void* d_ws, size_t ws_size,
                              hipStream_t stream)
{
  const int D=1024, DFF=2048, BS=4096;
  const float* x      = (const float*)d_in[0];
  const int*   mask   = (const int*)d_in[1];
  const float* alpha1 = (const float*)d_in[2];
  const float* bias1  = (const float*)d_in[3];
  const float* Wq     = (const float*)d_in[4];
  const float* bq     = (const float*)d_in[5];
  const float* Wk     = (const float*)d_in[6];
  const float* bk     = (const float*)d_in[7];
  const float* Wv     = (const float*)d_in[8];
  const float* bv     = (const float*)d_in[9];
  const float* Wo     = (const float*)d_in[10];
  const float* bo     = (const float*)d_in[11];
  const float* alpha2 = (const float*)d_in[12];
  const float* bias2  = (const float*)d_in[13];
  const float* W1     = (const float*)d_in[14];
  const float* b1     = (const float*)d_in[15];
  const float* W2     = (const float*)d_in[16];
  const float* b2     = (const float*)d_in[17];
  float* outp = (float*)d_out;

  char* ws = (char*)d_ws;
  size_t off = 0;
  auto alloc = [&](size_t bytes){ void* p = ws+off; off += (bytes+255)&~(size_t)255; return p; };
  unsigned short* x2b    = (unsigned short*)alloc((size_t)BS*D*2);
  unsigned short* qB     = (unsigned short*)alloc((size_t)BS*D*2);
  unsigned short* kB     = (unsigned short*)alloc((size_t)BS*D*2);
  unsigned short* vT     = (unsigned short*)alloc((size_t)BS*D*2);
  unsigned short* attnB  = (unsigned short*)alloc((size_t)BS*D*2);
  unsigned short* h1     = (unsigned short*)alloc((size_t)BS*DFF*2);
  float*          xres   = (float*)alloc((size_t)BS*D*4);
  unsigned short* wqkvT  = (unsigned short*)alloc((size_t)3*D*D*2);
  unsigned short* woT    = (unsigned short*)alloc((size_t)D*D*2);
  unsigned short* w1T    = (unsigned short*)alloc((size_t)D*DFF*2);
  unsigned short* w2T    = (unsigned short*)alloc((size_t)DFF*D*2);
  unsigned char*  flg    = (unsigned char*)alloc(2048);
  unsigned short* Opart  = (unsigned short*)alloc((size_t)2*BS*D*2);
  float*          mlbuf  = (float*)alloc((size_t)2*BS*16*2*4);

  preprocess<<<14336, 256, 0, stream>>>(Wq, Wk, Wv, Wo, W1, W2,
                                        mask, x, alpha1, bias1,
                                        wqkvT, woT, w1T, w2T, flg, x2b);

  gemm_qkv<<<dim3(BS/128, 24), 256, 0, stream>>>(x2b, wqkvT, bq, bk, bv, qB, kB, vT);

  attn_kernel<<<1024, 256, 0, stream>>>(qB, kB, vT, mask, flg, Opart, mlbuf);
  attn_combine<<<4096, 256, 0, stream>>>(Opart, mlbuf, attnB);

  gemm64_bk64<1><<<dim3(BS/64, D/128), 256, 0, stream>>>(attnB, woT, bo, x, nullptr, xres, BS, D, D);

  ln_kernel<<<BS, 256, 0, stream>>>(xres, alpha2, bias2, x2b);

  gemm64_bk64<2><<<dim3(BS/64, DFF/128), 256, 0, stream>>>(x2b, w1T, b1, nullptr, h1, nullptr, BS, DFF, D);
  gemm64_bk64<3><<<dim3(BS/64, D/128), 256, 0, stream>>>(h1, w2T, b2, xres, nullptr, outp, BS, D, DFF);
}

// Round 23
// 237.680 us; speedup vs baseline: 1.0230x; 1.0230x over previous
//
#include <hip/hip_runtime.h>
#include <math.h>

typedef __attribute__((ext_vector_type(8))) short v8s;
typedef __attribute__((ext_vector_type(4))) float v4f;
typedef __attribute__((ext_vector_type(2))) float v2f;
typedef __attribute__((ext_vector_type(16))) float v16f;
typedef __attribute__((ext_vector_type(4))) unsigned int v4u;
typedef __attribute__((ext_vector_type(2))) unsigned int v2u;

#define MFMA16(a,b,c) __builtin_amdgcn_mfma_f32_16x16x32_bf16(a,b,c,0,0,0)
#define MFMA32(a,b,c) __builtin_amdgcn_mfma_f32_32x32x16_bf16(a,b,c,0,0,0)
#define QSCALE 0.18033688011112042f  /* 0.125 * log2(e) */
#define MFIX   12.0f                 /* fixed softmax shift (exp2 domain) */

typedef const __attribute__((address_space(1))) void* gp1_t;
typedef __attribute__((address_space(3))) void* lp3_t;
__device__ __forceinline__ void gll16(const void* g, void* l){
  __builtin_amdgcn_global_load_lds((gp1_t)g, (lp3_t)l, 16, 0, 0);
}
#define VMCNT(n) asm volatile("s_waitcnt vmcnt(" #n ")" ::: "memory")

__device__ __forceinline__ unsigned short f2b(float f){
  unsigned u = __builtin_bit_cast(unsigned, f);
  u += 0x7FFFu + ((u>>16)&1u);
  return (unsigned short)(u>>16);
}
__device__ __forceinline__ float b2f(unsigned short u){
  return __builtin_bit_cast(float, ((unsigned)u)<<16);
}
__device__ __forceinline__ unsigned cvtpk(float lo, float hi){
  unsigned r;
  asm("v_cvt_pk_bf16_f32 %0, %1, %2" : "=v"(r) : "v"(lo), "v"(hi));
  return r;
}
__device__ __forceinline__ float gelu_exact(float x){
  return 0.5f*x*(1.0f + erff(x*0.70710678118654752f));
}

// ---------------- LayerNorm (ddof=1, sd+eps) -> bf16 out (used for ln2) ----
__global__ __launch_bounds__(256) void ln_kernel(const float* __restrict__ x,
    const float* __restrict__ alpha, const float* __restrict__ bias,
    unsigned short* __restrict__ out)
{
  const int D = 1024;
  int row = blockIdx.x;
  int tid = threadIdx.x;
  const float* xr = x + (size_t)row*D;
  v4f v = ((const v4f*)xr)[tid];
  float s  = v[0]+v[1]+v[2]+v[3];
  float s2 = v[0]*v[0]+v[1]*v[1]+v[2]*v[2]+v[3]*v[3];
  #pragma unroll
  for (int off=1; off<64; off<<=1){ s += __shfl_xor(s, off); s2 += __shfl_xor(s2, off); }
  __shared__ float red[8];
  int w = tid>>6;
  if ((tid&63)==0){ red[w]=s; red[4+w]=s2; }
  __syncthreads();
  s  = red[0]+red[1]+red[2]+red[3];
  s2 = red[4]+red[5]+red[6]+red[7];
  float mu  = s*(1.0f/D);
  float var = (s2 - (float)D*mu*mu)*(1.0f/(D-1));
  float inv = 1.0f/(sqrtf(fmaxf(var,0.0f)) + 1e-6f);
  v4f a  = ((const v4f*)alpha)[tid];
  v4f bi = ((const v4f*)bias)[tid];
  unsigned short o[4];
  #pragma unroll
  for (int i=0;i<4;i++) o[i] = f2b(a[i]*(v[i]-mu)*inv + bi[i]);
  v2u pk; pk[0] = (unsigned)o[0] | ((unsigned)o[1]<<16);
          pk[1] = (unsigned)o[2] | ((unsigned)o[3]<<16);
  ((v2u*)(out + (size_t)row*D))[tid] = pk;
}

// ---- fused prologue: weight transposes + mask flags + ln1, block-ranged ----
__global__ __launch_bounds__(256) void preprocess(
    const float* __restrict__ Wq, const float* __restrict__ Wk,
    const float* __restrict__ Wv, const float* __restrict__ Wo,
    const float* __restrict__ W1, const float* __restrict__ W2,
    const int* __restrict__ mask, const float* __restrict__ x,
    const float* __restrict__ alpha1, const float* __restrict__ bias1,
    unsigned short* __restrict__ wqkvT, unsigned short* __restrict__ woT,
    unsigned short* __restrict__ w1T, unsigned short* __restrict__ w2T,
    unsigned char* __restrict__ flags, unsigned short* __restrict__ x2b)
{
  __shared__ float t[32][33];
  __shared__ float red[8];
  __shared__ int f[4];
  int bid = blockIdx.x;
  int tid = threadIdx.x;
  if (bid < 8192){
    const float* in; unsigned short* out; int K, N, idx;
    if (bid < 3072){
      int m = bid >> 10; idx = bid & 1023;
      in = (m==0)?Wq:(m==1)?Wk:Wv; out = wqkvT + (size_t)m*1024*1024; K=1024; N=1024;
    } else if (bid < 4096){ idx = bid-3072; in=Wo; out=woT; K=1024; N=1024; }
    else if (bid < 6144){   idx = bid-4096; in=W1; out=w1T; K=1024; N=2048; }
    else {                  idx = bid-6144; in=W2; out=w2T; K=2048; N=1024; }
    int ntiles = N >> 5;
    int n0 = (idx % ntiles)*32, k0 = (idx / ntiles)*32;
    int tx = tid & 31, ty = tid >> 5;
    #pragma unroll
    for (int j=0;j<4;j++) t[ty+8*j][tx] = in[(size_t)(k0+ty+8*j)*N + n0+tx];
    __syncthreads();
    #pragma unroll
    for (int j=0;j<4;j++) out[(size_t)(n0+ty+8*j)*K + k0+tx] = f2b(t[tx][ty+8*j]);
  } else if (bid < 10240){
    const int S = 2048;
    int idx = bid - 8192;
    int kt = idx & 31, qt = (idx>>5)&31, b = idx>>10;
    const int* mp = mask + (size_t)b*S*S + (size_t)(qt*64)*S + kt*64;
    int ok = 1;
    #pragma unroll
    for (int i=0;i<16;i++){
      int e = tid + i*256;
      int row = e>>6, col = e&63;
      ok &= (mp[(size_t)row*S + col] != 0);
    }
    ok = __all(ok) ? 1 : 0;
    if ((tid&63)==0) f[tid>>6] = ok;
    __syncthreads();
    if (tid==0) flags[idx] = (unsigned char)(f[0]&f[1]&f[2]&f[3]);
  } else {
    const int D = 1024;
    int row = bid - 10240;
    const float* xr = x + (size_t)row*D;
    v4f v = ((const v4f*)xr)[tid];
    float s  = v[0]+v[1]+v[2]+v[3];
    float s2 = v[0]*v[0]+v[1]*v[1]+v[2]*v[2]+v[3]*v[3];
    #pragma unroll
    for (int off=1; off<64; off<<=1){ s += __shfl_xor(s, off); s2 += __shfl_xor(s2, off); }
    int w = tid>>6;
    if ((tid&63)==0){ red[w]=s; red[4+w]=s2; }
    __syncthreads();
    s  = red[0]+red[1]+red[2]+red[3];
    s2 = red[4]+red[5]+red[6]+red[7];
    float mu  = s*(1.0f/D);
    float var = (s2 - (float)D*mu*mu)*(1.0f/(D-1));
    float inv = 1.0f/(sqrtf(fmaxf(var,0.0f)) + 1e-6f);
    v4f a  = ((const v4f*)alpha1)[tid];
    v4f bi = ((const v4f*)bias1)[tid];
    unsigned short o[4];
    #pragma unroll
    for (int i=0;i<4;i++) o[i] = f2b(a[i]*(v[i]-mu)*inv + bi[i]);
    v2u pk; pk[0] = (unsigned)o[0] | ((unsigned)o[1]<<16);
            pk[1] = (unsigned)o[2] | ((unsigned)o[3]<<16);
    ((v2u*)(x2b + (size_t)row*D))[tid] = pk;
  }
}

// ---------------- fused QKV GEMM (128², 3buf); V written directly as vT -----
__global__ __launch_bounds__(256) void gemm_qkv(
    const unsigned short* __restrict__ A, const unsigned short* __restrict__ Bt,
    const float* __restrict__ bq, const float* __restrict__ bk, const float* __restrict__ bv,
    unsigned short* __restrict__ qB, unsigned short* __restrict__ kB,
    unsigned short* __restrict__ vT)
{
  const int K = 1024, N = 1024;
  __shared__ unsigned short As[3][128][32];
  __shared__ unsigned short Bs[3][128][32];
  int m0 = blockIdx.x*128;
  int ny = blockIdx.y;              // 0..23
  int seg = ny>>3;
  int n0g = ny*128;
  int tid = threadIdx.x;
  int w = tid>>6, l = tid&63;
  int wm = (w>>1)*64, wn = (w&1)*64;
  int r16 = l&15, kq = l>>4;
  v4f acc[4][4] = {};
  int t4 = tid>>2, c8 = (tid&3)*8;
  const unsigned short* Ag = A  + (size_t)(m0 + t4)*K + c8;
  const unsigned short* Bg = Bt + (size_t)(n0g + t4)*K + c8;
  auto stageG = [&](int kb, int idx){
    char* a = (char*)&As[idx][0][0] + w*1024;
    char* b = (char*)&Bs[idx][0][0] + w*1024;
    gll16(Ag + kb,                a);
    gll16(Ag + (size_t)64*K + kb, a + 4096);
    gll16(Bg + kb,                b);
    gll16(Bg + (size_t)64*K + kb, b + 4096);
  };
  const int nk = K/32;
  stageG(0, 0); stageG(32, 1);
  for (int i=0; i<nk; i++){
    int cur = i%3;
    if (i+1 < nk) VMCNT(4); else VMCNT(0);
    __builtin_amdgcn_s_barrier();
    if (i+2 < nk) stageG((i+2)*32, (i+2)%3);
    v8s a[4], b[4];
    #pragma unroll
    for (int mi=0;mi<4;mi++) a[mi] = *(const v8s*)&As[cur][wm+mi*16+r16][kq*8];
    #pragma unroll
    for (int ni=0;ni<4;ni++) b[ni] = *(const v8s*)&Bs[cur][wn+ni*16+r16][kq*8];
    #pragma unroll
    for (int mi=0;mi<4;mi++)
      #pragma unroll
      for (int ni=0;ni<4;ni++)
        acc[mi][ni] = MFMA16(a[mi], b[ni], acc[mi][ni]);
  }
  int ncol0 = (ny&7)*128;
  if (seg < 2){
    unsigned short* ob = (seg==0) ? qB : kB;
    const float*    bp = (seg==0) ? bq : bk;
    float sc = (seg==0) ? QSCALE : 1.0f;
    #pragma unroll
    for (int mi=0;mi<4;mi++){
      #pragma unroll
      for (int ni=0;ni<4;ni++){
        int col = ncol0 + wn + ni*16 + r16;
        float bvv = bp[col];
        #pragma unroll
        for (int r=0;r<4;r++){
          int row = m0 + wm + mi*16 + kq*4 + r;
          ob[(size_t)row*N + col] = f2b((acc[mi][ni][r] + bvv)*sc);
        }
      }
    }
  } else {
    #pragma unroll
    for (int mi=0;mi<4;mi++){
      #pragma unroll
      for (int ni=0;ni<4;ni++){
        int col = ncol0 + wn + ni*16 + r16;
        int hh = col >> 6, dk = col & 63;
        float bvv = bv[col];
        int row = m0 + wm + mi*16 + kq*4;    // r = 0..3 consecutive
        int bb = row >> 11, s = row & 2047;
        v2u pk;
        pk[0] = cvtpk(acc[mi][ni][0]+bvv, acc[mi][ni][1]+bvv);
        pk[1] = cvtpk(acc[mi][ni][2]+bvv, acc[mi][ni][3]+bvv);
        *(v2u*)(vT + ((size_t)(bb*16+hh)*64 + dk)*2048 + s) = pk;
      }
    }
  }
}

// ---------------- 64x128 GEMM, BK=32 (3buf, counted vmcnt) — used for FF1 ---
// MODE 2: outb = bf16(gelu(acc+bias))
template<int MODE>
__global__ __launch_bounds__(256) void gemm64_bt(
    const unsigned short* __restrict__ A, const unsigned short* __restrict__ Bt,
    const float* __restrict__ bias, const float* __restrict__ res,
    unsigned short* __restrict__ outb, float* __restrict__ outf,
    int M, int N, int K)
{
  __shared__ unsigned short As[3][64][32];
  __shared__ unsigned short Bs[3][128][32];
  int m0 = blockIdx.x*64, n0 = blockIdx.y*128;
  int tid = threadIdx.x;
  int w = tid>>6, l = tid&63;
  int wm = (w>>1)*32, wn = (w&1)*64;
  int r16 = l&15, kq = l>>4;
  v4f acc[2][4] = {};
  int t4 = tid>>2, c8 = (tid&3)*8;
  const unsigned short* Ag = A  + (size_t)(m0 + t4)*K + c8;
  const unsigned short* Bg = Bt + (size_t)(n0 + t4)*K + c8;
  auto stageG = [&](int kb, int idx){
    char* a = (char*)&As[idx][0][0] + w*1024;
    char* b = (char*)&Bs[idx][0][0] + w*1024;
    gll16(Ag + kb,                a);
    gll16(Bg + kb,                b);
    gll16(Bg + (size_t)64*K + kb, b + 4096);
  };
  const int nk = K/32;
  stageG(0, 0); stageG(32, 1);
  for (int i=0; i<nk; i++){
    int cur = i%3;
    if (i+1 < nk) VMCNT(3); else VMCNT(0);
    __builtin_amdgcn_s_barrier();
    if (i+2 < nk) stageG((i+2)*32, (i+2)%3);
    v8s a[2], b[4];
    #pragma unroll
    for (int mi=0;mi<2;mi++) a[mi] = *(const v8s*)&As[cur][wm+mi*16+r16][kq*8];
    #pragma unroll
    for (int ni=0;ni<4;ni++) b[ni] = *(const v8s*)&Bs[cur][wn+ni*16+r16][kq*8];
    #pragma unroll
    for (int mi=0;mi<2;mi++)
      #pragma unroll
      for (int ni=0;ni<4;ni++)
        acc[mi][ni] = MFMA16(a[mi], b[ni], acc[mi][ni]);
  }
  #pragma unroll
  for (int mi=0;mi<2;mi++){
    #pragma unroll
    for (int ni=0;ni<4;ni++){
      int col = n0 + wn + ni*16 + r16;
      float bv = bias[col];
      #pragma unroll
      for (int r=0;r<4;r++){
        int row = m0 + wm + mi*16 + kq*4 + r;
        float t = acc[mi][ni][r] + bv;
        if (MODE==2) t = gelu_exact(t);
        if (MODE==2) outb[(size_t)row*N + col] = f2b(t);
        else         outf[(size_t)row*N + col] = t + res[(size_t)row*N + col];
      }
    }
  }
}

// ---- 64x128 GEMM, BK=64, XOR-swizzled LDS (grid-capped 2/CU: Wo, FF2) ------
// Per-wave staging: wave w stages A rows w*16..+15, B rows w*32..+31.
// MODE 1: outf = acc+bias+res ; MODE 3: outf = gelu(acc+bias)+res
template<int MODE>
__global__ __launch_bounds__(256) void gemm64_bk64(
    const unsigned short* __restrict__ A, const unsigned short* __restrict__ Bt,
    const float* __restrict__ bias, const float* __restrict__ res,
    float* __restrict__ outf, int M, int N, int K)
{
  __shared__ unsigned short As[3][64][64];    // 24 KB
  __shared__ unsigned short Bs[3][128][64];   // 48 KB
  int m0 = blockIdx.x*64, n0 = blockIdx.y*128;
  int tid = threadIdx.x;
  int w = tid>>6, l = tid&63;
  int wm = (w>>1)*32, wn = (w&1)*64;
  int r16 = l&15, kq = l>>4;
  v4f acc[2][4] = {};
  int srow8 = l>>3;                 // 0..7 within 8-row stripe
  int gsw   = (l&7) ^ srow8;        // pre-swizzled source granule (rule #21)
  auto stageG = [&](int kb, int idx){
    #pragma unroll
    for (int sub=0; sub<2; sub++){
      int row = w*16 + sub*8 + srow8;
      gll16(A + (size_t)(m0+row)*K + kb + gsw*8, &As[idx][w*16+sub*8][0]);
    }
    #pragma unroll
    for (int sub=0; sub<4; sub++){
      int row = w*32 + sub*8 + srow8;
      gll16(Bt + (size_t)(n0+row)*K + kb + gsw*8, &Bs[idx][w*32+sub*8][0]);
    }
  };
  const int nk = K/64;
  stageG(0, 0); stageG(64, 1);
  int rx = r16 & 7;
  for (int i=0; i<nk; i++){
    int cur = i%3;
    if (i+1 < nk) VMCNT(6); else VMCNT(0);
    __builtin_amdgcn_s_barrier();
    if (i+2 < nk) stageG((i+2)*64, (i+2)%3);
    #pragma unroll
    for (int ks=0; ks<2; ks++){
      int gl = ((ks*4 + kq) ^ rx)*8;
      v8s a[2], b[4];
      #pragma unroll
      for (int mi=0;mi<2;mi++) a[mi] = *(const v8s*)&As[cur][wm+mi*16+r16][gl];
      #pragma unroll
      for (int ni=0;ni<4;ni++) b[ni] = *(const v8s*)&Bs[cur][wn+ni*16+r16][gl];
      #pragma unroll
      for (int mi=0;mi<2;mi++)
        #pragma unroll
        for (int ni=0;ni<4;ni++)
          acc[mi][ni] = MFMA16(a[mi], b[ni], acc[mi][ni]);
    }
  }
  #pragma unroll
  for (int mi=0;mi<2;mi++){
    #pragma unroll
    for (int ni=0;ni<4;ni++){
      int col = n0 + wn + ni*16 + r16;
      float bv = bias[col];
      #pragma unroll
      for (int r=0;r<4;r++){
        int row = m0 + wm + mi*16 + kq*4 + r;
        float t = acc[mi][ni][r] + bv;
        if (MODE==3) t = gelu_exact(t);
        outf[(size_t)row*N + col] = t + res[(size_t)row*N + col];
      }
    }
  }
}

// -------- flash attention, 2-way SPLIT-KV, fixed-shift softmax --------------
__global__ __launch_bounds__(256, 4) void attn_kernel(
    const unsigned short* __restrict__ Q, const unsigned short* __restrict__ Kb,
    const unsigned short* __restrict__ vT, const int* __restrict__ mask,
    const unsigned char* __restrict__ flags,
    unsigned short* __restrict__ Opart, float* __restrict__ ml)
{
  const int S = 2048, D = 1024;
  __shared__ unsigned short Kb2[2][64][64];   // 16 KB, granule-swizzled
  __shared__ unsigned short Vb2[2][64][64];   // 16 KB, granule-swizzled
  int bid = (blockIdx.x & 7)*128 + (blockIdx.x >> 3);   // 1024 blocks, bijective
  int half = bid & 1;
  int qt = (bid >> 1) & 15;     // 128-row q tile
  int bh = bid >> 5;
  int b = bh >> 4, h = bh & 15;
  int tid = threadIdx.x, w = tid>>6, l = tid&63;
  int l31 = l & 31, hi = l >> 5;
  int pidx = (l ^ 32) << 2;
  const unsigned short* Qp  = Q  + (size_t)b*S*D + h*64;
  const unsigned short* Kp  = Kb + (size_t)b*S*D + h*64;
  const unsigned short* vTp = vT + (size_t)bh*64*S;
  int qrow = qt*128 + w*32 + l31;
  v8s qfr[4];
  #pragma unroll
  for (int ks=0;ks<4;ks++)
    qfr[ks] = *(const v8s*)(Qp + (size_t)qrow*D + ks*16 + hi*8);
  float l_run = 0.0f;
  v16f o0 = {}, o1 = {};
  const int* mp = mask + (size_t)b*S*S;
  const unsigned char* fl = flags + ((size_t)b*32 + qt*2)*32;
  int kt0 = half*16;
  unsigned long long okmask = __ballot( l < 16 ? ((fl[kt0+l] & fl[32+kt0+l]) != 0) : 1 );

  int srow = l>>3;
  int gsw  = (l&7) ^ srow;
  auto stage = [&](int ktg, int idx){
    int kt64 = ktg*64;
    #pragma unroll
    for (int sub=0; sub<2; sub++){
      int row = w*16 + sub*8 + srow;
      gll16(Kp  + (size_t)(kt64+row)*D + gsw*8, &Kb2[idx][w*16+sub*8][0]);
      gll16(vTp + (size_t)row*S + kt64 + gsw*8, &Vb2[idx][w*16+sub*8][0]);
    }
  };
  auto bfrag = [&](unsigned a0, unsigned a1, unsigned a4, unsigned a5) -> v8s {
    unsigned p0 = (unsigned)__builtin_amdgcn_ds_bpermute(pidx, (int)a0);
    unsigned p1 = (unsigned)__builtin_amdgcn_ds_bpermute(pidx, (int)a1);
    unsigned p4 = (unsigned)__builtin_amdgcn_ds_bpermute(pidx, (int)a4);
    unsigned p5 = (unsigned)__builtin_amdgcn_ds_bpermute(pidx, (int)a5);
    v4u pw;
    pw[0] = hi ? p4 : a0;
    pw[1] = hi ? p5 : a1;
    pw[2] = hi ? a4 : p0;
    pw[3] = hi ? a5 : p1;
    return __builtin_bit_cast(v8s, pw);
  };

  stage(kt0, 0);
  int cur = 0;
  for (int it=0; it<16; it++){
    __syncthreads();
    if (it+1 < 16) stage(kt0+it+1, cur^1);
    int ktg = kt0 + it;
    int l7 = l & 7;
    v16f s0 = {}, s1 = {};
    __builtin_amdgcn_s_setprio(1);
    #pragma unroll
    for (int ks=0; ks<4; ks++){
      v8s kf0 = *(const v8s*)&Kb2[cur][l31     ][(((ks*2) + hi) ^ l7)*8];
      v8s kf1 = *(const v8s*)&Kb2[cur][32 + l31][(((ks*2) + hi) ^ l7)*8];
      s0 = MFMA32(kf0, qfr[ks], s0);
      s1 = MFMA32(kf1, qfr[ks], s1);
    }
    __builtin_amdgcn_s_setprio(0);
    if (((~okmask) >> it) & 1ull){
      #pragma unroll
      for (int r=0;r<16;r++){
        int kvl = (r&3) + 8*(r>>2) + 4*hi;
        if (mp[(size_t)qrow*S + ktg*64 + kvl]      == 0) s0[r] = -3.0e38f;
        if (mp[(size_t)qrow*S + ktg*64 + 32 + kvl] == 0) s1[r] = -3.0e38f;
      }
    }
    #pragma unroll
    for (int r=0;r<16;r++){
      s0[r] = exp2f(s0[r] - MFIX);
      s1[r] = exp2f(s1[r] - MFIX);
    }
    float a0 = ((s0[0]+s0[1])+(s0[2]+s0[3])) + ((s0[4]+s0[5])+(s0[6]+s0[7]));
    float a1 = ((s0[8]+s0[9])+(s0[10]+s0[11])) + ((s0[12]+s0[13])+(s0[14]+s0[15]));
    float a2 = ((s1[0]+s1[1])+(s1[2]+s1[3])) + ((s1[4]+s1[5])+(s1[6]+s1[7]));
    float a3 = ((s1[8]+s1[9])+(s1[10]+s1[11])) + ((s1[12]+s1[13])+(s1[14]+s1[15]));
    float rs = (a0+a1) + (a2+a3);
    rs += __shfl_xor(rs, 32);
    l_run += rs;
    v8s pb0 = bfrag(cvtpk(s0[0],s0[1]),  cvtpk(s0[2],s0[3]),
                    cvtpk(s0[4],s0[5]),  cvtpk(s0[6],s0[7]));
    v8s pb1 = bfrag(cvtpk(s0[8],s0[9]),  cvtpk(s0[10],s0[11]),
                    cvtpk(s0[12],s0[13]),cvtpk(s0[14],s0[15]));
    v8s pb2 = bfrag(cvtpk(s1[0],s1[1]),  cvtpk(s1[2],s1[3]),
                    cvtpk(s1[4],s1[5]),  cvtpk(s1[6],s1[7]));
    v8s pb3 = bfrag(cvtpk(s1[8],s1[9]),  cvtpk(s1[10],s1[11]),
                    cvtpk(s1[12],s1[13]),cvtpk(s1[14],s1[15]));
    __builtin_amdgcn_s_setprio(1);
    #pragma unroll
    for (int kvs=0; kvs<4; kvs++){
      v8s pb = (kvs==0) ? pb0 : (kvs==1) ? pb1 : (kvs==2) ? pb2 : pb3;
      v8s vv0 = *(const v8s*)&Vb2[cur][l31     ][(((kvs*2) + hi) ^ l7)*8];
      v8s vv1 = *(const v8s*)&Vb2[cur][32 + l31][(((kvs*2) + hi) ^ l7)*8];
      o0 = MFMA32(vv0, pb, o0);
      o1 = MFMA32(vv1, pb, o1);
    }
    __builtin_amdgcn_s_setprio(0);
    cur ^= 1;
  }
  int rowg = b*S + qrow;
  unsigned short* Op = Opart + (size_t)half*4096*1024 + (size_t)rowg*1024 + h*64;
  #pragma unroll
  for (int p=0; p<8; p++){
    int dk = (p&1)*2 + 8*(p>>1) + 4*hi;
    *(unsigned*)(Op + dk)      = cvtpk(o0[2*p], o0[2*p+1]);
    *(unsigned*)(Op + 32 + dk) = cvtpk(o1[2*p], o1[2*p+1]);
  }
  if (!hi){
    float* mlp = ml + ((size_t)half*4096 + rowg)*32 + h*2;
    mlp[0] = l_run;
  }
}

// ---------------- combine the two kv-half partials -> bf16 attnB ------------
__global__ __launch_bounds__(256) void attn_combine(const unsigned short* __restrict__ Opart,
    const float* __restrict__ ml, unsigned short* __restrict__ outB)
{
  int row = blockIdx.x;            // 0..4095
  int t = threadIdx.x;
  int col = t*4;
  int head = col >> 6;
  float l1 = ml[(size_t)row*32 + head*2];
  float l2 = ml[((size_t)4096 + row)*32 + head*2];
  float inv = 1.0f / (l1 + l2);
  v2u au = *(const v2u*)(Opart + (size_t)row*1024 + col);
  v2u bu = *(const v2u*)(Opart + (size_t)4096*1024 + (size_t)row*1024 + col);
  float a0 = b2f((unsigned short)(au[0]&0xffff)), a1 = b2f((unsigned short)(au[0]>>16));
  float a2 = b2f((unsigned short)(au[1]&0xffff)), a3 = b2f((unsigned short)(au[1]>>16));
  float c0 = b2f((unsigned short)(bu[0]&0xffff)), c1 = b2f((unsigned short)(bu[0]>>16));
  float c2 = b2f((unsigned short)(bu[1]&0xffff)), c3 = b2f((unsigned short)(bu[1]>>16));
  v2u pk;
  pk[0] = cvtpk((a0 + c0)*inv, (a1 + c1)*inv);
  pk[1] = cvtpk((a2 + c2)*inv, (a3 + c3)*inv);
  *(v2u*)(outB + (size_t)row*1024 + col) = pk;
}

// ---------------- launcher ----------------
extern "C" void kernel_launch(void* const* d_in, const int* in_sizes, int n_in,
                              void* d_out, int out_size, void* d_ws, size_t ws_size,
                              hipStream_t stream)
{
  const int D=1024, DFF=2048, BS=4096;
  const float* x      = (const float*)d_in[0];
  const int*   mask   = (const int*)d_in[1];
  const float* alpha1 = (const float*)d_in[2];
  const float* bias1  = (const float*)d_in[3];
  const float* Wq     = (const float*)d_in[4];
  const float* bq     = (const float*)d_in[5];
  const float* Wk     = (const float*)d_in[6];
  const float* bk     = (const float*)d_in[7];
  const float* Wv     = (const float*)d_in[8];
  const float* bv     = (const float*)d_in[9];
  const float* Wo     = (const float*)d_in[10];
  const float* bo     = (const float*)d_in[11];
  const float* alpha2 = (const float*)d_in[12];
  const float* bias2  = (const float*)d_in[13];
  const float* W1     = (const float*)d_in[14];
  const float* b1     = (const float*)d_in[15];
  const float* W2     = (const float*)d_in[16];
  const float* b2     = (const float*)d_in[17];
  float* outp = (float*)d_out;

  char* ws = (char*)d_ws;
  size_t off = 0;
  auto alloc = [&](size_t bytes){ void* p = ws+off; off += (bytes+255)&~(size_t)255; return p; };
  unsigned short* x2b    = (unsigned short*)alloc((size_t)BS*D*2);
  unsigned short* qB     = (unsigned short*)alloc((size_t)BS*D*2);
  unsigned short* kB     = (unsigned short*)alloc((size_t)BS*D*2);
  unsigned short* vT     = (unsigned short*)alloc((size_t)BS*D*2);
  unsigned short* attnB  = (unsigned short*)alloc((size_t)BS*D*2);
  unsigned short* h1     = (unsigned short*)alloc((size_t)BS*DFF*2);
  float*          xres   = (float*)alloc((size_t)BS*D*4);
  unsigned short* wqkvT  = (unsigned short*)alloc((size_t)3*D*D*2);
  unsigned short* woT    = (unsigned short*)alloc((size_t)D*D*2);
  unsigned short* w1T    = (unsigned short*)alloc((size_t)D*DFF*2);
  unsigned short* w2T    = (unsigned short*)alloc((size_t)DFF*D*2);
  unsigned char*  flg    = (unsigned char*)alloc(2048);
  unsigned short* Opart  = (unsigned short*)alloc((size_t)2*BS*D*2);
  float*          mlbuf  = (float*)alloc((size_t)2*BS*16*2*4);

  preprocess<<<14336, 256, 0, stream>>>(Wq, Wk, Wv, Wo, W1, W2,
                                        mask, x, alpha1, bias1,
                                        wqkvT, woT, w1T, w2T, flg, x2b);

  gemm_qkv<<<dim3(BS/128, 24), 256, 0, stream>>>(x2b, wqkvT, bq, bk, bv, qB, kB, vT);

  attn_kernel<<<1024, 256, 0, stream>>>(qB, kB, vT, mask, flg, Opart, mlbuf);
  attn_combine<<<4096, 256, 0, stream>>>(Opart, mlbuf, attnB);

  gemm64_bk64<1><<<dim3(BS/64, D/128), 256, 0, stream>>>(attnB, woT, bo, x, xres, BS, D, D);

  ln_kernel<<<BS, 256, 0, stream>>>(xres, alpha2, bias2, x2b);

  gemm64_bt<2><<<dim3(BS/64, DFF/128), 256, 0, stream>>>(x2b, w1T, b1, nullptr, h1, nullptr, BS, DFF, D);
  gemm64_bk64<3><<<dim3(BS/64, D/128), 256, 0, stream>>>(h1, w2T, b2, xres, outp, BS, D, DFF);
}